// Round 1
// baseline (1611.545 us; speedup 1.0000x reference)
//
#include <hip/hip_runtime.h>
#include <hip/hip_bf16.h>
#include <hip/hip_fp16.h>

// Problem constants
#define B_   64
#define SWP  512
#define D_   768
#define W_   256     // NUM_WORDS
#define H_   256
#define G4   1024    // 4*H
#define N2   2048    // both dirs' gates
#define M_   16384   // B_*W_ rows
#define A_   8
#define KK_  4

typedef __attribute__((ext_vector_type(4))) float f32x4;
typedef __attribute__((ext_vector_type(8))) short bf16x8;
typedef _Float16 __attribute__((ext_vector_type(2))) h2_t;

__device__ __forceinline__ void gload_lds16(const void* g, void* l) {
  __builtin_amdgcn_global_load_lds((const __attribute__((address_space(1))) void*)g,
                                   (__attribute__((address_space(3))) void*)l, 16, 0, 0);
}

__device__ __forceinline__ float sigm(float x) { return 1.f / (1.f + __expf(-x)); }
__device__ __forceinline__ float tanh_(float x) { return 1.f - 2.f / (1.f + __expf(2.f * x)); }

__device__ __forceinline__ float dot2acc(h2_t w, h2_t h, float acc) {
#if __has_builtin(__builtin_amdgcn_fdot2)
  return __builtin_amdgcn_fdot2(w, h, acc, false);
#else
  return acc + (float)w[0] * (float)h[0] + (float)w[1] * (float)h[1];
#endif
}

// K1: scatter-mean wordpieces -> words (bf16). One block per (b, word).
__global__ __launch_bounds__(256) void k_words(const float* __restrict__ emb,
                                               const int* __restrict__ mask,
                                               __hip_bfloat16* __restrict__ words) {
  const int b = blockIdx.x >> 8;
  const int w = blockIdx.x & 255;
  const int tid = threadIdx.x;
  __shared__ int m[SWP];
  m[tid] = mask[b * SWP + tid];
  m[tid + 256] = mask[b * SWP + 256 + tid];
  __syncthreads();
  // lower_bound(w), lower_bound(w+1) on sorted row
  int lo = 0, hi = SWP;
  while (lo < hi) { int mid = (lo + hi) >> 1; if (m[mid] < w) lo = mid + 1; else hi = mid; }
  int lo2 = lo, hi2 = SWP;
  while (lo2 < hi2) { int mid = (lo2 + hi2) >> 1; if (m[mid] < w + 1) lo2 = mid + 1; else hi2 = mid; }
  const int cnt = lo2 - lo;
  const float inv = (cnt > 0) ? 1.f / (float)cnt : 0.f;
  float s0 = 0.f, s1 = 0.f, s2 = 0.f;
  for (int s = lo; s < lo2; ++s) {
    const float* row = emb + ((size_t)b * SWP + s) * D_;
    s0 += row[tid]; s1 += row[tid + 256]; s2 += row[tid + 512];
  }
  __hip_bfloat16* o = words + ((size_t)b * W_ + w) * D_;
  o[tid]       = __float2bfloat16(s0 * inv);
  o[tid + 256] = __float2bfloat16(s1 * inv);
  o[tid + 512] = __float2bfloat16(s2 * inv);
}

// K2a: concat+convert input weights to bf16 [2048][768]; fused bias b_ih+b_hh [2048]
__global__ __launch_bounds__(256) void k_prep_wih(const float* __restrict__ wf, const float* __restrict__ wr,
                                                  const float* __restrict__ bihf, const float* __restrict__ bhhf,
                                                  const float* __restrict__ bihr, const float* __restrict__ bhhr,
                                                  __hip_bfloat16* __restrict__ wih, float* __restrict__ bias) {
  const int i = blockIdx.x * 256 + threadIdx.x;   // 2048*768 total
  const int n = i / D_;
  const int k = i - n * D_;
  const float v = (n < G4) ? wf[n * D_ + k] : wr[(n - G4) * D_ + k];
  wih[i] = __float2bfloat16(v);
  if (i < N2) {
    bias[i] = (i < G4) ? (bihf[i] + bhhf[i]) : (bihr[i - G4] + bhhr[i - G4]);
  }
}

// K2b: repack w_hh as half2 [dir][128][1024]: whhP[d][kk][r] = (w[r][2kk], w[r][2kk+1])
__global__ __launch_bounds__(256) void k_prep_whh(const float* __restrict__ whf,
                                                  const float* __restrict__ whr,
                                                  h2_t* __restrict__ whhP) {
  const int i = blockIdx.x * 256 + threadIdx.x;   // 2*128*1024
  const int d = i >> 17;
  const int kk = (i >> 10) & 127;
  const int r = i & 1023;
  const float* w = d ? whr : whf;
  h2_t v;
  v[0] = (_Float16)w[r * H_ + 2 * kk];
  v[1] = (_Float16)w[r * H_ + 2 * kk + 1];
  whhP[i] = v;
}

// K3: xg = words @ W_ih^T + (b_ih + b_hh), bf16 MFMA, 128x128 tile, out f16
__global__ __launch_bounds__(256) void k_gemm_xg(const __hip_bfloat16* __restrict__ A,   // [M_][768]
                                                 const __hip_bfloat16* __restrict__ Wt,  // [2048][768]
                                                 const float* __restrict__ bias,         // [2048]
                                                 _Float16* __restrict__ C) {             // [M_][2048]
  const int bm = blockIdx.y * 128;
  const int bn = blockIdx.x * 128;
  __shared__ __hip_bfloat16 As[128 * 32];
  __shared__ __hip_bfloat16 Bs[128 * 32];
  const int tid = threadIdx.x;
  const int lane = tid & 63;
  const int wave = tid >> 6;
  const int wm = (wave >> 1) * 64;
  const int wn = (wave & 1) * 64;
  const int l15 = lane & 15;
  const int l4 = lane >> 4;
  const int row_a = tid >> 2;   // 0..63
  const int chunk = tid & 3;    // 16B chunk
  f32x4 acc[4][4] = {};
  for (int k0 = 0; k0 < D_; k0 += 32) {
    const __hip_bfloat16* ga  = A  + (size_t)(bm + row_a) * D_ + k0 + chunk * 8;
    const __hip_bfloat16* ga2 = A  + (size_t)(bm + 64 + row_a) * D_ + k0 + chunk * 8;
    const __hip_bfloat16* gb  = Wt + (size_t)(bn + row_a) * D_ + k0 + chunk * 8;
    const __hip_bfloat16* gb2 = Wt + (size_t)(bn + 64 + row_a) * D_ + k0 + chunk * 8;
    gload_lds16(ga,  As + tid * 8);
    gload_lds16(ga2, As + 2048 + tid * 8);
    gload_lds16(gb,  Bs + tid * 8);
    gload_lds16(gb2, Bs + 2048 + tid * 8);
    __syncthreads();
    bf16x8 af[4], bf[4];
#pragma unroll
    for (int i = 0; i < 4; ++i) {
      af[i] = *(const bf16x8*)(As + (wm + i * 16 + l15) * 32 + l4 * 8);
      bf[i] = *(const bf16x8*)(Bs + (wn + i * 16 + l15) * 32 + l4 * 8);
    }
#pragma unroll
    for (int i = 0; i < 4; ++i)
#pragma unroll
      for (int j = 0; j < 4; ++j)
        acc[i][j] = __builtin_amdgcn_mfma_f32_16x16x32_bf16(af[i], bf[j], acc[i][j], 0, 0, 0);
    __syncthreads();
  }
#pragma unroll
  for (int i = 0; i < 4; ++i) {
    const int m = bm + wm + i * 16 + l4 * 4;
#pragma unroll
    for (int j = 0; j < 4; ++j) {
      const int n = bn + wn + j * 16 + l15;
      const float bs = bias[n];
#pragma unroll
      for (int r = 0; r < 4; ++r)
        C[(size_t)(m + r) * N2 + n] = (_Float16)(acc[i][j][r] + bs);
    }
  }
}

// K4: BiLSTM recurrence. Block = (dir, batch). 512 threads.
// t<256: unit u -> gate rows i(u), g(512+u). t>=256: f(256+u), o(768+u).
__global__ __launch_bounds__(512) void k_lstm(const _Float16* __restrict__ xg,   // [M_][2048]
                                              const h2_t* __restrict__ whhP,     // [2][128][1024]
                                              float* __restrict__ out) {         // [B_][W_][512]
  const int bx = blockIdx.x;
  const int d = bx & 1;
  const int b = bx >> 1;
  const int t = threadIdx.x;
  const int u = t & 255;
  const bool lowhalf = (t < 256);
  const int r1 = lowhalf ? u : (256 + u);
  const int r2 = r1 + 512;
  const h2_t* wp = whhP + (size_t)d * 128 * 1024;
  __shared__ h2_t h2s[128];
  __shared__ float fo[256][2];
  __shared__ float hF[256];
  float c = 0.f;
  if (t < 128) { h2_t z; z[0] = (_Float16)0.f; z[1] = (_Float16)0.f; h2s[t] = z; }
  __syncthreads();
  for (int step = 0; step < W_; ++step) {
    const int tt = d ? (W_ - 1 - step) : step;
    const _Float16* xrow = xg + ((size_t)b * W_ + tt) * N2 + d * G4;
    float a1 = (float)xrow[r1];
    float a2 = (float)xrow[r2];
    if (step > 0) {
#pragma unroll 4
      for (int kk = 0; kk < 128; ++kk) {
        const h2_t hp = h2s[kk];
        const h2_t w1 = wp[kk * 1024 + r1];
        const h2_t w2 = wp[kk * 1024 + r2];
        a1 = dot2acc(w1, hp, a1);
        a2 = dot2acc(w2, hp, a2);
      }
    }
    if (!lowhalf) { fo[u][0] = a1; fo[u][1] = a2; }
    __syncthreads();
    if (lowhalf) {
      const float ig = sigm(a1);
      const float gg = tanh_(a2);
      const float fg = sigm(fo[u][0]);
      const float og = sigm(fo[u][1]);
      c = fg * c + ig * gg;
      const float h = og * tanh_(c);
      out[((size_t)b * W_ + tt) * 512 + d * 256 + u] = h;
      hF[u] = h;
    }
    __syncthreads();
    if (t < 128) {
      h2_t v; v[0] = (_Float16)hF[2 * t]; v[1] = (_Float16)hF[2 * t + 1];
      h2s[t] = v;
    }
    __syncthreads();
  }
}

// K5: sent-mean + aspect gather-mean + fc1(relu) + fc2. One block per batch.
__global__ __launch_bounds__(256) void k_head(const float* __restrict__ out,   // [B_][W_][512]
                                              const int* __restrict__ aidx,    // [B_][8][4]
                                              const float* __restrict__ fc1w,  // [256][1024]
                                              const float* __restrict__ fc1b,
                                              const float* __restrict__ fc2w,  // [4][256]
                                              const float* __restrict__ fc2b,
                                              float* __restrict__ logits) {    // [B_][8][4]
  const int b = blockIdx.x;
  const int t = threadIdx.x;
  __shared__ float emb[A_][1024];
  __shared__ float h1[A_][256];
  __shared__ float sent[512];
  const float* ob = out + (size_t)b * W_ * 512;
  float s0 = 0.f, s1 = 0.f;
  for (int tt = 0; tt < W_; ++tt) {
    s0 += ob[tt * 512 + t];
    s1 += ob[tt * 512 + 256 + t];
  }
  sent[t] = s0 * (1.f / 256.f);
  sent[t + 256] = s1 * (1.f / 256.f);
  __syncthreads();
  for (int a = 0; a < A_; ++a) {
    int nv = 0;
    float m0 = 0.f, m1 = 0.f;
    for (int k = 0; k < KK_; ++k) {
      const int idx = aidx[(b * A_ + a) * KK_ + k];
      if (idx >= 0) {
        const int tt = min(idx, W_ - 2) + 1;
        m0 += ob[tt * 512 + t];
        m1 += ob[tt * 512 + 256 + t];
        nv++;
      }
    }
    const float inv = nv > 0 ? 1.f / (float)nv : 0.f;
    const bool valid = nv > 0;
    emb[a][t]        = valid ? sent[t] : 0.f;
    emb[a][t + 256]  = valid ? sent[t + 256] : 0.f;
    emb[a][512 + t]       = m0 * inv;
    emb[a][512 + 256 + t] = m1 * inv;
  }
  __syncthreads();
  {
    float acc[A_];
#pragma unroll
    for (int a = 0; a < A_; ++a) acc[a] = fc1b[t];
    const float* wrow = fc1w + (size_t)t * 1024;
    for (int j = 0; j < 1024; j += 4) {
      const float4 w = *(const float4*)(wrow + j);
#pragma unroll
      for (int a = 0; a < A_; ++a) {
        const float4 e = *(const float4*)(&emb[a][j]);
        acc[a] += w.x * e.x + w.y * e.y + w.z * e.z + w.w * e.w;
      }
    }
#pragma unroll
    for (int a = 0; a < A_; ++a) h1[a][t] = fmaxf(acc[a], 0.f);
  }
  __syncthreads();
  if (t < A_ * 4) {
    const int a = t >> 2, l = t & 3;
    float acc = fc2b[l];
    const float* w = fc2w + l * 256;
    for (int j = 0; j < 256; ++j) acc += w[j] * h1[a][j];
    logits[(b * A_ + a) * 4 + l] = acc;
  }
}

extern "C" void kernel_launch(void* const* d_in, const int* in_sizes, int n_in,
                              void* d_out, int out_size, void* d_ws, size_t ws_size,
                              hipStream_t stream) {
  const float* emb  = (const float*)d_in[0];
  const int*   mask = (const int*)d_in[1];
  const int*   aidx = (const int*)d_in[2];
  const float* wihf = (const float*)d_in[3];
  const float* whhf = (const float*)d_in[4];
  const float* bihf = (const float*)d_in[5];
  const float* bhhf = (const float*)d_in[6];
  const float* wihr = (const float*)d_in[7];
  const float* whhr = (const float*)d_in[8];
  const float* bihr = (const float*)d_in[9];
  const float* bhhr = (const float*)d_in[10];
  const float* fc1w = (const float*)d_in[11];
  const float* fc1b = (const float*)d_in[12];
  const float* fc2w = (const float*)d_in[13];
  const float* fc2b = (const float*)d_in[14];
  float* logits = (float*)d_out;

  char* ws = (char*)d_ws;
  size_t off = 0;
  auto alloc = [&](size_t bytes) -> void* {
    void* p = ws + off;
    off += (bytes + 255) & ~(size_t)255;
    return p;
  };
  __hip_bfloat16* words = (__hip_bfloat16*)alloc((size_t)M_ * D_ * 2);        // 25.2 MB
  _Float16*       xg    = (_Float16*)alloc((size_t)M_ * N2 * 2);              // 67.1 MB
  __hip_bfloat16* wih   = (__hip_bfloat16*)alloc((size_t)N2 * D_ * 2);        // 3.1 MB
  float*          bias  = (float*)alloc((size_t)N2 * 4);
  h2_t*           whhP  = (h2_t*)alloc((size_t)2 * 128 * 1024 * 4);           // 1.0 MB
  float*          outh  = (float*)alloc((size_t)B_ * W_ * 512 * 4);           // 33.6 MB

  k_words<<<B_ * W_, 256, 0, stream>>>(emb, mask, words);
  k_prep_wih<<<(N2 * D_) / 256, 256, 0, stream>>>(wihf, wihr, bihf, bhhf, bihr, bhhr, wih, bias);
  k_prep_whh<<<(2 * 128 * 1024) / 256, 256, 0, stream>>>(whhf, whhr, whhP);
  dim3 gg(N2 / 128, M_ / 128);
  k_gemm_xg<<<gg, 256, 0, stream>>>(words, wih, bias, xg);
  k_lstm<<<B_ * 2, 512, 0, stream>>>(xg, whhP, outh);
  k_head<<<B_, 256, 0, stream>>>(outh, aidx, fc1w, fc1b, fc2w, fc2b, logits);
}

// Round 3
// 670.644 us; speedup vs baseline: 2.4030x; 2.4030x over previous
//
#include <hip/hip_runtime.h>
#include <hip/hip_bf16.h>
#include <hip/hip_fp16.h>

// Problem constants
#define B_   64
#define SWP  512
#define D_   768
#define W_   256     // NUM_WORDS
#define H_   256
#define G4   1024    // 4*H
#define N2   2048    // both dirs' gates
#define M_   16384   // B_*W_ rows
#define A_   8
#define KK_  4

typedef __attribute__((ext_vector_type(4))) float f32x4;
typedef __attribute__((ext_vector_type(8))) short bf16x8;
typedef _Float16 __attribute__((ext_vector_type(2))) h2_t;

#define KREG2 96   // h2 (k-pairs) kept in registers per gate row  (k = 0..191)
#define KLDS2 32   // h2 kept in LDS per gate row                  (k = 192..255)

__device__ __forceinline__ void gload_lds16(const void* g, void* l) {
  __builtin_amdgcn_global_load_lds((const __attribute__((address_space(1))) void*)g,
                                   (__attribute__((address_space(3))) void*)l, 16, 0, 0);
}

__device__ __forceinline__ float sigm(float x) { return 1.f / (1.f + __expf(-x)); }
__device__ __forceinline__ float tanh_(float x) { return 1.f - 2.f / (1.f + __expf(2.f * x)); }

__device__ __forceinline__ float dot2acc(h2_t w, h2_t h, float acc) {
#if __has_builtin(__builtin_amdgcn_fdot2)
  return __builtin_amdgcn_fdot2(w, h, acc, false);
#else
  return acc + (float)w[0] * (float)h[0] + (float)w[1] * (float)h[1];
#endif
}

// K1: scatter-mean wordpieces -> words (bf16). One block per (b, word).
__global__ __launch_bounds__(256) void k_words(const float* __restrict__ emb,
                                               const int* __restrict__ mask,
                                               __hip_bfloat16* __restrict__ words) {
  const int b = blockIdx.x >> 8;
  const int w = blockIdx.x & 255;
  const int tid = threadIdx.x;
  __shared__ int m[SWP];
  m[tid] = mask[b * SWP + tid];
  m[tid + 256] = mask[b * SWP + 256 + tid];
  __syncthreads();
  int lo = 0, hi = SWP;
  while (lo < hi) { int mid = (lo + hi) >> 1; if (m[mid] < w) lo = mid + 1; else hi = mid; }
  int lo2 = lo, hi2 = SWP;
  while (lo2 < hi2) { int mid = (lo2 + hi2) >> 1; if (m[mid] < w + 1) lo2 = mid + 1; else hi2 = mid; }
  const int cnt = lo2 - lo;
  const float inv = (cnt > 0) ? 1.f / (float)cnt : 0.f;
  float s0 = 0.f, s1 = 0.f, s2 = 0.f;
  for (int s = lo; s < lo2; ++s) {
    const float* row = emb + ((size_t)b * SWP + s) * D_;
    s0 += row[tid]; s1 += row[tid + 256]; s2 += row[tid + 512];
  }
  __hip_bfloat16* o = words + ((size_t)b * W_ + w) * D_;
  o[tid]       = __float2bfloat16(s0 * inv);
  o[tid + 256] = __float2bfloat16(s1 * inv);
  o[tid + 512] = __float2bfloat16(s2 * inv);
}

// K2a: concat+convert input weights to bf16 [2048][768]; fused bias b_ih+b_hh [2048]
__global__ __launch_bounds__(256) void k_prep_wih(const float* __restrict__ wf, const float* __restrict__ wr,
                                                  const float* __restrict__ bihf, const float* __restrict__ bhhf,
                                                  const float* __restrict__ bihr, const float* __restrict__ bhhr,
                                                  __hip_bfloat16* __restrict__ wih, float* __restrict__ bias) {
  const int i = blockIdx.x * 256 + threadIdx.x;
  const int n = i / D_;
  const int k = i - n * D_;
  const float v = (n < G4) ? wf[n * D_ + k] : wr[(n - G4) * D_ + k];
  wih[i] = __float2bfloat16(v);
  if (i < N2) {
    bias[i] = (i < G4) ? (bihf[i] + bhhf[i]) : (bihr[i - G4] + bhhr[i - G4]);
  }
}

// K2b: repack w_hh as half2 [dir][128 kk][1024 r]: whhP[d][kk][r] = (w[r][2kk], w[r][2kk+1])
__global__ __launch_bounds__(256) void k_prep_whh(const float* __restrict__ whf,
                                                  const float* __restrict__ whr,
                                                  h2_t* __restrict__ whhP) {
  const int i = blockIdx.x * 256 + threadIdx.x;   // 2*128*1024
  const int d = i >> 17;
  const int kk = (i >> 10) & 127;
  const int r = i & 1023;
  const float* w = d ? whr : whf;
  h2_t v;
  v[0] = (_Float16)w[r * H_ + 2 * kk];
  v[1] = (_Float16)w[r * H_ + 2 * kk + 1];
  whhP[i] = v;
}

// K3: xg = words @ W_ih^T + (b_ih + b_hh), bf16 MFMA, 128x128 tile, out f16
__global__ __launch_bounds__(256) void k_gemm_xg(const __hip_bfloat16* __restrict__ A,
                                                 const __hip_bfloat16* __restrict__ Wt,
                                                 const float* __restrict__ bias,
                                                 _Float16* __restrict__ C) {
  const int bm = blockIdx.y * 128;
  const int bn = blockIdx.x * 128;
  __shared__ __hip_bfloat16 As[128 * 32];
  __shared__ __hip_bfloat16 Bs[128 * 32];
  const int tid = threadIdx.x;
  const int lane = tid & 63;
  const int wave = tid >> 6;
  const int wm = (wave >> 1) * 64;
  const int wn = (wave & 1) * 64;
  const int l15 = lane & 15;
  const int l4 = lane >> 4;
  const int row_a = tid >> 2;
  const int chunk = tid & 3;
  f32x4 acc[4][4] = {};
  for (int k0 = 0; k0 < D_; k0 += 32) {
    const __hip_bfloat16* ga  = A  + (size_t)(bm + row_a) * D_ + k0 + chunk * 8;
    const __hip_bfloat16* ga2 = A  + (size_t)(bm + 64 + row_a) * D_ + k0 + chunk * 8;
    const __hip_bfloat16* gb  = Wt + (size_t)(bn + row_a) * D_ + k0 + chunk * 8;
    const __hip_bfloat16* gb2 = Wt + (size_t)(bn + 64 + row_a) * D_ + k0 + chunk * 8;
    gload_lds16(ga,  As + tid * 8);
    gload_lds16(ga2, As + 2048 + tid * 8);
    gload_lds16(gb,  Bs + tid * 8);
    gload_lds16(gb2, Bs + 2048 + tid * 8);
    __syncthreads();
    bf16x8 af[4], bf[4];
#pragma unroll
    for (int i = 0; i < 4; ++i) {
      af[i] = *(const bf16x8*)(As + (wm + i * 16 + l15) * 32 + l4 * 8);
      bf[i] = *(const bf16x8*)(Bs + (wn + i * 16 + l15) * 32 + l4 * 8);
    }
#pragma unroll
    for (int i = 0; i < 4; ++i)
#pragma unroll
      for (int j = 0; j < 4; ++j)
        acc[i][j] = __builtin_amdgcn_mfma_f32_16x16x32_bf16(af[i], bf[j], acc[i][j], 0, 0, 0);
    __syncthreads();
  }
#pragma unroll
  for (int i = 0; i < 4; ++i) {
    const int m = bm + wm + i * 16 + l4 * 4;
#pragma unroll
    for (int j = 0; j < 4; ++j) {
      const int n = bn + wn + j * 16 + l15;
      const float bs = bias[n];
#pragma unroll
      for (int r = 0; r < 4; ++r)
        C[(size_t)(m + r) * N2 + n] = (_Float16)(acc[i][j][r] + bs);
    }
  }
}

// K4 v3: BiLSTM recurrence with register/LDS-resident weights.
// Block = (dir, batch), 512 threads. Thread t owns gate rows r1=t, r2=512+t.
// Weights: k-pairs 0..95 per row in VGPRs (2 rows => 192 VGPRs),
//          k-pairs 96..127 per row in LDS (16 chunks x 512 thr x 4 h2 = 128 KB).
__global__ __launch_bounds__(512, 2) void k_lstm(const _Float16* __restrict__ xg,   // [M_][2048]
                                                 const h2_t* __restrict__ whhP,     // [2][128][1024]
                                                 float* __restrict__ out) {         // [B_][W_][512]
  const int bx = blockIdx.x;
  const int d = bx & 1;
  const int b = bx >> 1;
  const int t = threadIdx.x;
  const int u = t & 255;
  const bool low = (t < 256);

  __shared__ __align__(16) _Float16 hbuf[256];        // 128 h2
  __shared__ __align__(16) h2_t wlds[16][512][4];     // 128 KB
  __shared__ float fo[256][2];

  const h2_t* wp = whhP + (size_t)d * (128 * 1024);
  // One-time: load register-resident weights (coalesced: fixed kk, consecutive rows)
  h2_t wr1[KREG2], wr2[KREG2];
#pragma unroll
  for (int kk = 0; kk < KREG2; ++kk) {
    wr1[kk] = wp[kk * 1024 + t];
    wr2[kk] = wp[kk * 1024 + 512 + t];
  }
  // One-time: stage LDS-resident weight tail, k-pairs 96..127 for both rows.
  // chunk c: row = (c<8)? r1 : r2; k-pairs kb..kb+3 with kb = 96+(c&7)*4.
#pragma unroll
  for (int c = 0; c < 16; ++c) {
    const int row = (c < 8) ? t : (512 + t);
    const int kb = KREG2 + (c & 7) * 4;
    h2_t v0 = wp[(kb + 0) * 1024 + row];
    h2_t v1 = wp[(kb + 1) * 1024 + row];
    h2_t v2 = wp[(kb + 2) * 1024 + row];
    h2_t v3 = wp[(kb + 3) * 1024 + row];
    wlds[c][t][0] = v0; wlds[c][t][1] = v1; wlds[c][t][2] = v2; wlds[c][t][3] = v3;
  }
  if (t < 256) hbuf[t] = (_Float16)0.f;
  __syncthreads();

  float c_state = 0.f;
  for (int step = 0; step < W_; ++step) {
    const int tt = d ? (W_ - 1 - step) : step;
    const _Float16* xrow = xg + ((size_t)b * W_ + tt) * N2 + d * G4;
    const float xv1 = (float)xrow[t];
    const float xv2 = (float)xrow[512 + t];
    float a1 = 0.f, a2 = 0.f;
    if (step > 0) {
      // register part: k-pairs 0..95, 24 chunks of 4 h2 (16B h broadcast each)
#pragma unroll
      for (int cc = 0; cc < KREG2 / 4; ++cc) {
        const f32x4 hv = *(const f32x4*)&hbuf[cc * 8];
        const h2_t* hp = (const h2_t*)&hv;
#pragma unroll
        for (int j = 0; j < 4; ++j) {
          a1 = dot2acc(wr1[cc * 4 + j], hp[j], a1);
          a2 = dot2acc(wr2[cc * 4 + j], hp[j], a2);
        }
      }
      // LDS part: k-pairs 96..127 (8 chunks of 4 h2 per row)
#pragma unroll
      for (int cb = 0; cb < 8; ++cb) {
        const f32x4 hv = *(const f32x4*)&hbuf[(KREG2 + cb * 4) * 2];
        const f32x4 w1v = *(const f32x4*)&wlds[cb][t][0];
        const f32x4 w2v = *(const f32x4*)&wlds[8 + cb][t][0];
        const h2_t* hp = (const h2_t*)&hv;
        const h2_t* w1p = (const h2_t*)&w1v;
        const h2_t* w2p = (const h2_t*)&w2v;
#pragma unroll
        for (int j = 0; j < 4; ++j) {
          a1 = dot2acc(w1p[j], hp[j], a1);
          a2 = dot2acc(w2p[j], hp[j], a2);
        }
      }
    }
    a1 += xv1; a2 += xv2;
    if (!low) { fo[u][0] = a1; fo[u][1] = a2; }
    __syncthreads();
    if (low) {
      const float ig = sigm(a1);
      const float gg = tanh_(a2);
      const float fg = sigm(fo[u][0]);
      const float og = sigm(fo[u][1]);
      c_state = fg * c_state + ig * gg;
      const float h = og * tanh_(c_state);
      out[((size_t)b * W_ + tt) * 512 + d * 256 + u] = h;
      hbuf[u] = (_Float16)h;
    }
    __syncthreads();
  }
}

// K5: sent-mean + aspect gather-mean + fc1(relu) + fc2. One block per batch.
__global__ __launch_bounds__(256) void k_head(const float* __restrict__ out,
                                              const int* __restrict__ aidx,
                                              const float* __restrict__ fc1w,
                                              const float* __restrict__ fc1b,
                                              const float* __restrict__ fc2w,
                                              const float* __restrict__ fc2b,
                                              float* __restrict__ logits) {
  const int b = blockIdx.x;
  const int t = threadIdx.x;
  __shared__ float emb[A_][1024];
  __shared__ float h1[A_][256];
  __shared__ float sent[512];
  const float* ob = out + (size_t)b * W_ * 512;
  float s0 = 0.f, s1 = 0.f;
  for (int tt = 0; tt < W_; ++tt) {
    s0 += ob[tt * 512 + t];
    s1 += ob[tt * 512 + 256 + t];
  }
  sent[t] = s0 * (1.f / 256.f);
  sent[t + 256] = s1 * (1.f / 256.f);
  __syncthreads();
  for (int a = 0; a < A_; ++a) {
    int nv = 0;
    float m0 = 0.f, m1 = 0.f;
    for (int k = 0; k < KK_; ++k) {
      const int idx = aidx[(b * A_ + a) * KK_ + k];
      if (idx >= 0) {
        const int tt = min(idx, W_ - 2) + 1;
        m0 += ob[tt * 512 + t];
        m1 += ob[tt * 512 + 256 + t];
        nv++;
      }
    }
    const float inv = nv > 0 ? 1.f / (float)nv : 0.f;
    const bool valid = nv > 0;
    emb[a][t]        = valid ? sent[t] : 0.f;
    emb[a][t + 256]  = valid ? sent[t + 256] : 0.f;
    emb[a][512 + t]       = m0 * inv;
    emb[a][512 + 256 + t] = m1 * inv;
  }
  __syncthreads();
  {
    float acc[A_];
#pragma unroll
    for (int a = 0; a < A_; ++a) acc[a] = fc1b[t];
    const float* wrow = fc1w + (size_t)t * 1024;
    for (int j = 0; j < 1024; j += 4) {
      const float4 w = *(const float4*)(wrow + j);
#pragma unroll
      for (int a = 0; a < A_; ++a) {
        const float4 e = *(const float4*)(&emb[a][j]);
        acc[a] += w.x * e.x + w.y * e.y + w.z * e.z + w.w * e.w;
      }
    }
#pragma unroll
    for (int a = 0; a < A_; ++a) h1[a][t] = fmaxf(acc[a], 0.f);
  }
  __syncthreads();
  if (t < A_ * 4) {
    const int a = t >> 2, l = t & 3;
    float acc = fc2b[l];
    const float* w = fc2w + l * 256;
    for (int j = 0; j < 256; ++j) acc += w[j] * h1[a][j];
    logits[(b * A_ + a) * 4 + l] = acc;
  }
}

extern "C" void kernel_launch(void* const* d_in, const int* in_sizes, int n_in,
                              void* d_out, int out_size, void* d_ws, size_t ws_size,
                              hipStream_t stream) {
  const float* emb  = (const float*)d_in[0];
  const int*   mask = (const int*)d_in[1];
  const int*   aidx = (const int*)d_in[2];
  const float* wihf = (const float*)d_in[3];
  const float* whhf = (const float*)d_in[4];
  const float* bihf = (const float*)d_in[5];
  const float* bhhf = (const float*)d_in[6];
  const float* wihr = (const float*)d_in[7];
  const float* whhr = (const float*)d_in[8];
  const float* bihr = (const float*)d_in[9];
  const float* bhhr = (const float*)d_in[10];
  const float* fc1w = (const float*)d_in[11];
  const float* fc1b = (const float*)d_in[12];
  const float* fc2w = (const float*)d_in[13];
  const float* fc2b = (const float*)d_in[14];
  float* logits = (float*)d_out;

  char* ws = (char*)d_ws;
  size_t off = 0;
  auto alloc = [&](size_t bytes) -> void* {
    void* p = ws + off;
    off += (bytes + 255) & ~(size_t)255;
    return p;
  };
  __hip_bfloat16* words = (__hip_bfloat16*)alloc((size_t)M_ * D_ * 2);
  _Float16*       xg    = (_Float16*)alloc((size_t)M_ * N2 * 2);
  __hip_bfloat16* wih   = (__hip_bfloat16*)alloc((size_t)N2 * D_ * 2);
  float*          bias  = (float*)alloc((size_t)N2 * 4);
  h2_t*           whhP  = (h2_t*)alloc((size_t)2 * 128 * 1024 * 4);
  float*          outh  = (float*)alloc((size_t)B_ * W_ * 512 * 4);

  k_words<<<B_ * W_, 256, 0, stream>>>(emb, mask, words);
  k_prep_wih<<<(N2 * D_) / 256, 256, 0, stream>>>(wihf, wihr, bihf, bhhf, bihr, bhhr, wih, bias);
  k_prep_whh<<<(2 * 128 * 1024) / 256, 256, 0, stream>>>(whhf, whhr, whhP);
  dim3 gg(N2 / 128, M_ / 128);
  k_gemm_xg<<<gg, 256, 0, stream>>>(words, wih, bias, xg);
  k_lstm<<<B_ * 2, 512, 0, stream>>>(xg, whhP, outh);
  k_head<<<B_, 256, 0, stream>>>(outh, aidx, fc1w, fc1b, fc2w, fc2b, logits);
}

// Round 4
// 668.526 us; speedup vs baseline: 2.4106x; 1.0032x over previous
//
#include <hip/hip_runtime.h>
#include <hip/hip_bf16.h>
#include <hip/hip_fp16.h>

// Problem constants
#define B_   64
#define SWP  512
#define D_   768
#define W_   256     // NUM_WORDS
#define H_   256
#define G4   1024    // 4*H
#define N2   2048    // both dirs' gates
#define M_   16384   // B_*W_ rows
#define A_   8
#define KK_  4

typedef __attribute__((ext_vector_type(4))) float f32x4;
typedef __attribute__((ext_vector_type(8))) short bf16x8;
typedef _Float16 __attribute__((ext_vector_type(2))) h2_t;

#define KREG2 96   // h2 (k-pairs) kept in registers per gate row  (k = 0..191)
#define KLDS2 32   // h2 kept in LDS per gate row                  (k = 192..255)

__device__ __forceinline__ void gload_lds16(const void* g, void* l) {
  __builtin_amdgcn_global_load_lds((const __attribute__((address_space(1))) void*)g,
                                   (__attribute__((address_space(3))) void*)l, 16, 0, 0);
}

__device__ __forceinline__ float sigm(float x) { return 1.f / (1.f + __expf(-x)); }
__device__ __forceinline__ float tanh_(float x) { return 1.f - 2.f / (1.f + __expf(2.f * x)); }

__device__ __forceinline__ float dot2acc(h2_t w, h2_t h, float acc) {
#if __has_builtin(__builtin_amdgcn_fdot2)
  return __builtin_amdgcn_fdot2(w, h, acc, false);
#else
  return acc + (float)w[0] * (float)h[0] + (float)w[1] * (float)h[1];
#endif
}

// K1: scatter-mean wordpieces -> words (bf16). One block per (b, word).
__global__ __launch_bounds__(256) void k_words(const float* __restrict__ emb,
                                               const int* __restrict__ mask,
                                               __hip_bfloat16* __restrict__ words) {
  const int b = blockIdx.x >> 8;
  const int w = blockIdx.x & 255;
  const int tid = threadIdx.x;
  __shared__ int m[SWP];
  m[tid] = mask[b * SWP + tid];
  m[tid + 256] = mask[b * SWP + 256 + tid];
  __syncthreads();
  int lo = 0, hi = SWP;
  while (lo < hi) { int mid = (lo + hi) >> 1; if (m[mid] < w) lo = mid + 1; else hi = mid; }
  int lo2 = lo, hi2 = SWP;
  while (lo2 < hi2) { int mid = (lo2 + hi2) >> 1; if (m[mid] < w + 1) lo2 = mid + 1; else hi2 = mid; }
  const int cnt = lo2 - lo;
  const float inv = (cnt > 0) ? 1.f / (float)cnt : 0.f;
  float s0 = 0.f, s1 = 0.f, s2 = 0.f;
  for (int s = lo; s < lo2; ++s) {
    const float* row = emb + ((size_t)b * SWP + s) * D_;
    s0 += row[tid]; s1 += row[tid + 256]; s2 += row[tid + 512];
  }
  __hip_bfloat16* o = words + ((size_t)b * W_ + w) * D_;
  o[tid]       = __float2bfloat16(s0 * inv);
  o[tid + 256] = __float2bfloat16(s1 * inv);
  o[tid + 512] = __float2bfloat16(s2 * inv);
}

// K2a: concat+convert input weights to bf16 [2048][768]; fused bias b_ih+b_hh [2048]
__global__ __launch_bounds__(256) void k_prep_wih(const float* __restrict__ wf, const float* __restrict__ wr,
                                                  const float* __restrict__ bihf, const float* __restrict__ bhhf,
                                                  const float* __restrict__ bihr, const float* __restrict__ bhhr,
                                                  __hip_bfloat16* __restrict__ wih, float* __restrict__ bias) {
  const int i = blockIdx.x * 256 + threadIdx.x;
  const int n = i / D_;
  const int k = i - n * D_;
  const float v = (n < G4) ? wf[n * D_ + k] : wr[(n - G4) * D_ + k];
  wih[i] = __float2bfloat16(v);
  if (i < N2) {
    bias[i] = (i < G4) ? (bihf[i] + bhhf[i]) : (bihr[i - G4] + bhhr[i - G4]);
  }
}

// K2b: repack w_hh as half2 [dir][128 kk][1024 r]: whhP[d][kk][r] = (w[r][2kk], w[r][2kk+1])
__global__ __launch_bounds__(256) void k_prep_whh(const float* __restrict__ whf,
                                                  const float* __restrict__ whr,
                                                  h2_t* __restrict__ whhP) {
  const int i = blockIdx.x * 256 + threadIdx.x;   // 2*128*1024
  const int d = i >> 17;
  const int kk = (i >> 10) & 127;
  const int r = i & 1023;
  const float* w = d ? whr : whf;
  h2_t v;
  v[0] = (_Float16)w[r * H_ + 2 * kk];
  v[1] = (_Float16)w[r * H_ + 2 * kk + 1];
  whhP[i] = v;
}

// K3: xg = words @ W_ih^T + (b_ih + b_hh), bf16 MFMA, 128x128 tile, out f16
__global__ __launch_bounds__(256) void k_gemm_xg(const __hip_bfloat16* __restrict__ A,
                                                 const __hip_bfloat16* __restrict__ Wt,
                                                 const float* __restrict__ bias,
                                                 _Float16* __restrict__ C) {
  const int bm = blockIdx.y * 128;
  const int bn = blockIdx.x * 128;
  __shared__ __hip_bfloat16 As[128 * 32];
  __shared__ __hip_bfloat16 Bs[128 * 32];
  const int tid = threadIdx.x;
  const int lane = tid & 63;
  const int wave = tid >> 6;
  const int wm = (wave >> 1) * 64;
  const int wn = (wave & 1) * 64;
  const int l15 = lane & 15;
  const int l4 = lane >> 4;
  const int row_a = tid >> 2;
  const int chunk = tid & 3;
  f32x4 acc[4][4] = {};
  for (int k0 = 0; k0 < D_; k0 += 32) {
    const __hip_bfloat16* ga  = A  + (size_t)(bm + row_a) * D_ + k0 + chunk * 8;
    const __hip_bfloat16* ga2 = A  + (size_t)(bm + 64 + row_a) * D_ + k0 + chunk * 8;
    const __hip_bfloat16* gb  = Wt + (size_t)(bn + row_a) * D_ + k0 + chunk * 8;
    const __hip_bfloat16* gb2 = Wt + (size_t)(bn + 64 + row_a) * D_ + k0 + chunk * 8;
    gload_lds16(ga,  As + tid * 8);
    gload_lds16(ga2, As + 2048 + tid * 8);
    gload_lds16(gb,  Bs + tid * 8);
    gload_lds16(gb2, Bs + 2048 + tid * 8);
    __syncthreads();
    bf16x8 af[4], bf[4];
#pragma unroll
    for (int i = 0; i < 4; ++i) {
      af[i] = *(const bf16x8*)(As + (wm + i * 16 + l15) * 32 + l4 * 8);
      bf[i] = *(const bf16x8*)(Bs + (wn + i * 16 + l15) * 32 + l4 * 8);
    }
#pragma unroll
    for (int i = 0; i < 4; ++i)
#pragma unroll
      for (int j = 0; j < 4; ++j)
        acc[i][j] = __builtin_amdgcn_mfma_f32_16x16x32_bf16(af[i], bf[j], acc[i][j], 0, 0, 0);
    __syncthreads();
  }
#pragma unroll
  for (int i = 0; i < 4; ++i) {
    const int m = bm + wm + i * 16 + l4 * 4;
#pragma unroll
    for (int j = 0; j < 4; ++j) {
      const int n = bn + wn + j * 16 + l15;
      const float bs = bias[n];
#pragma unroll
      for (int r = 0; r < 4; ++r)
        C[(size_t)(m + r) * N2 + n] = (_Float16)(acc[i][j][r] + bs);
    }
  }
}

// K4 v4: BiLSTM recurrence with register/LDS-resident weights.
// Block = (dir, batch), 512 threads. Thread t owns gate rows r1=t, r2=512+t.
// Weights: k-pairs 0..95 per row in VGPRs (2 rows => 192 VGPRs),
//          k-pairs 96..127 per row in LDS (16 chunks x 512 thr x 4 h2 = 128 KB).
// amdgpu_waves_per_eu(2,2): pin allocator to the 256-VGPR tier so the 192
// weight registers stay resident (round-3 run allocated 128 and spilled,
// costing ~1.5us/step of L2 scratch reload).
__global__ __launch_bounds__(512)
__attribute__((amdgpu_waves_per_eu(2, 2)))
void k_lstm(const _Float16* __restrict__ xg,   // [M_][2048]
            const h2_t* __restrict__ whhP,     // [2][128][1024]
            float* __restrict__ out) {         // [B_][W_][512]
  const int bx = blockIdx.x;
  const int d = bx & 1;
  const int b = bx >> 1;
  const int t = threadIdx.x;
  const int u = t & 255;
  const bool low = (t < 256);

  __shared__ __align__(16) _Float16 hbuf[256];        // 128 h2
  __shared__ __align__(16) h2_t wlds[16][512][4];     // 128 KB
  __shared__ float fo[256][2];

  const h2_t* wp = whhP + (size_t)d * (128 * 1024);
  // One-time: load register-resident weights (coalesced: fixed kk, consecutive rows)
  h2_t wr1[KREG2], wr2[KREG2];
#pragma unroll
  for (int kk = 0; kk < KREG2; ++kk) {
    wr1[kk] = wp[kk * 1024 + t];
    wr2[kk] = wp[kk * 1024 + 512 + t];
  }
  // One-time: stage LDS-resident weight tail, k-pairs 96..127 for both rows.
#pragma unroll
  for (int c = 0; c < 16; ++c) {
    const int row = (c < 8) ? t : (512 + t);
    const int kb = KREG2 + (c & 7) * 4;
    h2_t v0 = wp[(kb + 0) * 1024 + row];
    h2_t v1 = wp[(kb + 1) * 1024 + row];
    h2_t v2 = wp[(kb + 2) * 1024 + row];
    h2_t v3 = wp[(kb + 3) * 1024 + row];
    wlds[c][t][0] = v0; wlds[c][t][1] = v1; wlds[c][t][2] = v2; wlds[c][t][3] = v3;
  }
  if (t < 256) hbuf[t] = (_Float16)0.f;
  __syncthreads();

  float c_state = 0.f;
  for (int step = 0; step < W_; ++step) {
    const int tt = d ? (W_ - 1 - step) : step;
    const _Float16* xrow = xg + ((size_t)b * W_ + tt) * N2 + d * G4;
    const float xv1 = (float)xrow[t];
    const float xv2 = (float)xrow[512 + t];
    // 4 accumulator chains (2 per gate row) to keep fdot2 latency off the
    // critical path (64-deep chain x 4cyc < issue time).
    float a1a = 0.f, a1b = 0.f, a2a = 0.f, a2b = 0.f;
    if (step > 0) {
      // register part: k-pairs 0..95, 24 chunks of 4 h2 (16B h broadcast each)
#pragma unroll
      for (int cc = 0; cc < KREG2 / 4; ++cc) {
        const f32x4 hv = *(const f32x4*)&hbuf[cc * 8];
        const h2_t* hp = (const h2_t*)&hv;
        a1a = dot2acc(wr1[cc * 4 + 0], hp[0], a1a);
        a1b = dot2acc(wr1[cc * 4 + 1], hp[1], a1b);
        a2a = dot2acc(wr2[cc * 4 + 0], hp[0], a2a);
        a2b = dot2acc(wr2[cc * 4 + 1], hp[1], a2b);
        a1a = dot2acc(wr1[cc * 4 + 2], hp[2], a1a);
        a1b = dot2acc(wr1[cc * 4 + 3], hp[3], a1b);
        a2a = dot2acc(wr2[cc * 4 + 2], hp[2], a2a);
        a2b = dot2acc(wr2[cc * 4 + 3], hp[3], a2b);
      }
      // LDS part: k-pairs 96..127 (8 chunks of 4 h2 per row)
#pragma unroll
      for (int cb = 0; cb < 8; ++cb) {
        const f32x4 hv = *(const f32x4*)&hbuf[(KREG2 + cb * 4) * 2];
        const f32x4 w1v = *(const f32x4*)&wlds[cb][t][0];
        const f32x4 w2v = *(const f32x4*)&wlds[8 + cb][t][0];
        const h2_t* hp = (const h2_t*)&hv;
        const h2_t* w1p = (const h2_t*)&w1v;
        const h2_t* w2p = (const h2_t*)&w2v;
        a1a = dot2acc(w1p[0], hp[0], a1a);
        a1b = dot2acc(w1p[1], hp[1], a1b);
        a2a = dot2acc(w2p[0], hp[0], a2a);
        a2b = dot2acc(w2p[1], hp[1], a2b);
        a1a = dot2acc(w1p[2], hp[2], a1a);
        a1b = dot2acc(w1p[3], hp[3], a1b);
        a2a = dot2acc(w2p[2], hp[2], a2a);
        a2b = dot2acc(w2p[3], hp[3], a2b);
      }
    }
    const float a1 = a1a + a1b + xv1;
    const float a2 = a2a + a2b + xv2;
    if (!low) { fo[u][0] = a1; fo[u][1] = a2; }
    __syncthreads();
    if (low) {
      const float ig = sigm(a1);
      const float gg = tanh_(a2);
      const float fg = sigm(fo[u][0]);
      const float og = sigm(fo[u][1]);
      c_state = fg * c_state + ig * gg;
      const float h = og * tanh_(c_state);
      out[((size_t)b * W_ + tt) * 512 + d * 256 + u] = h;
      hbuf[u] = (_Float16)h;
    }
    __syncthreads();
  }
}

// K5: sent-mean + aspect gather-mean + fc1(relu) + fc2. One block per batch.
__global__ __launch_bounds__(256) void k_head(const float* __restrict__ out,
                                              const int* __restrict__ aidx,
                                              const float* __restrict__ fc1w,
                                              const float* __restrict__ fc1b,
                                              const float* __restrict__ fc2w,
                                              const float* __restrict__ fc2b,
                                              float* __restrict__ logits) {
  const int b = blockIdx.x;
  const int t = threadIdx.x;
  __shared__ float emb[A_][1024];
  __shared__ float h1[A_][256];
  __shared__ float sent[512];
  const float* ob = out + (size_t)b * W_ * 512;
  float s0 = 0.f, s1 = 0.f;
  for (int tt = 0; tt < W_; ++tt) {
    s0 += ob[tt * 512 + t];
    s1 += ob[tt * 512 + 256 + t];
  }
  sent[t] = s0 * (1.f / 256.f);
  sent[t + 256] = s1 * (1.f / 256.f);
  __syncthreads();
  for (int a = 0; a < A_; ++a) {
    int nv = 0;
    float m0 = 0.f, m1 = 0.f;
    for (int k = 0; k < KK_; ++k) {
      const int idx = aidx[(b * A_ + a) * KK_ + k];
      if (idx >= 0) {
        const int tt = min(idx, W_ - 2) + 1;
        m0 += ob[tt * 512 + t];
        m1 += ob[tt * 512 + 256 + t];
        nv++;
      }
    }
    const float inv = nv > 0 ? 1.f / (float)nv : 0.f;
    const bool valid = nv > 0;
    emb[a][t]        = valid ? sent[t] : 0.f;
    emb[a][t + 256]  = valid ? sent[t + 256] : 0.f;
    emb[a][512 + t]       = m0 * inv;
    emb[a][512 + 256 + t] = m1 * inv;
  }
  __syncthreads();
  {
    float acc[A_];
#pragma unroll
    for (int a = 0; a < A_; ++a) acc[a] = fc1b[t];
    const float* wrow = fc1w + (size_t)t * 1024;
    for (int j = 0; j < 1024; j += 4) {
      const float4 w = *(const float4*)(wrow + j);
#pragma unroll
      for (int a = 0; a < A_; ++a) {
        const float4 e = *(const float4*)(&emb[a][j]);
        acc[a] += w.x * e.x + w.y * e.y + w.z * e.z + w.w * e.w;
      }
    }
#pragma unroll
    for (int a = 0; a < A_; ++a) h1[a][t] = fmaxf(acc[a], 0.f);
  }
  __syncthreads();
  if (t < A_ * 4) {
    const int a = t >> 2, l = t & 3;
    float acc = fc2b[l];
    const float* w = fc2w + l * 256;
    for (int j = 0; j < 256; ++j) acc += w[j] * h1[a][j];
    logits[(b * A_ + a) * 4 + l] = acc;
  }
}

extern "C" void kernel_launch(void* const* d_in, const int* in_sizes, int n_in,
                              void* d_out, int out_size, void* d_ws, size_t ws_size,
                              hipStream_t stream) {
  const float* emb  = (const float*)d_in[0];
  const int*   mask = (const int*)d_in[1];
  const int*   aidx = (const int*)d_in[2];
  const float* wihf = (const float*)d_in[3];
  const float* whhf = (const float*)d_in[4];
  const float* bihf = (const float*)d_in[5];
  const float* bhhf = (const float*)d_in[6];
  const float* wihr = (const float*)d_in[7];
  const float* whhr = (const float*)d_in[8];
  const float* bihr = (const float*)d_in[9];
  const float* bhhr = (const float*)d_in[10];
  const float* fc1w = (const float*)d_in[11];
  const float* fc1b = (const float*)d_in[12];
  const float* fc2w = (const float*)d_in[13];
  const float* fc2b = (const float*)d_in[14];
  float* logits = (float*)d_out;

  char* ws = (char*)d_ws;
  size_t off = 0;
  auto alloc = [&](size_t bytes) -> void* {
    void* p = ws + off;
    off += (bytes + 255) & ~(size_t)255;
    return p;
  };
  __hip_bfloat16* words = (__hip_bfloat16*)alloc((size_t)M_ * D_ * 2);
  _Float16*       xg    = (_Float16*)alloc((size_t)M_ * N2 * 2);
  __hip_bfloat16* wih   = (__hip_bfloat16*)alloc((size_t)N2 * D_ * 2);
  float*          bias  = (float*)alloc((size_t)N2 * 4);
  h2_t*           whhP  = (h2_t*)alloc((size_t)2 * 128 * 1024 * 4);
  float*          outh  = (float*)alloc((size_t)B_ * W_ * 512 * 4);

  k_words<<<B_ * W_, 256, 0, stream>>>(emb, mask, words);
  k_prep_wih<<<(N2 * D_) / 256, 256, 0, stream>>>(wihf, wihr, bihf, bhhf, bihr, bhhr, wih, bias);
  k_prep_whh<<<(2 * 128 * 1024) / 256, 256, 0, stream>>>(whhf, whhr, whhP);
  dim3 gg(N2 / 128, M_ / 128);
  k_gemm_xg<<<gg, 256, 0, stream>>>(words, wih, bias, xg);
  k_lstm<<<B_ * 2, 512, 0, stream>>>(xg, whhP, outh);
  k_head<<<B_, 256, 0, stream>>>(outh, aidx, fc1w, fc1b, fc2w, fc2b, logits);
}